// Round 1
// baseline (4769.876 us; speedup 1.0000x reference)
//
#include <hip/hip_runtime.h>

#define N_NODES 40000
#define NE      640000
#define ND      128
#define ED      64
#define NH      8
#define DKV     16

// y = x @ W + b, x:[n,128] W:[128,128] b:[128]; 8 rows per block, 256 thr
__global__ __launch_bounds__(256) void proj128(const float* __restrict__ x,
                                               const float* __restrict__ W,
                                               const float* __restrict__ b,
                                               float* __restrict__ y, int n) {
  __shared__ float xs[8][ND];
  const int r0 = blockIdx.x * 8;
  const int tid = threadIdx.x;
  const int lr = tid >> 7;      // 0..1
  const int o  = tid & 127;     // out col
  for (int i = tid; i < 8 * ND; i += 256) {
    int rr = i >> 7, cc = i & 127;
    int gr = r0 + rr;
    xs[rr][cc] = (gr < n) ? x[(size_t)gr * ND + cc] : 0.f;
  }
  __syncthreads();
  float a0 = 0.f, a1 = 0.f, a2 = 0.f, a3 = 0.f;
#pragma unroll 8
  for (int k = 0; k < ND; ++k) {
    float w = W[k * ND + o];
    a0 = fmaf(xs[lr + 0][k], w, a0);
    a1 = fmaf(xs[lr + 2][k], w, a1);
    a2 = fmaf(xs[lr + 4][k], w, a2);
    a3 = fmaf(xs[lr + 6][k], w, a3);
  }
  const float bb = b[o];
  int r;
  r = r0 + lr + 0; if (r < n) y[(size_t)r * ND + o] = a0 + bb;
  r = r0 + lr + 2; if (r < n) y[(size_t)r * ND + o] = a1 + bb;
  r = r0 + lr + 4; if (r < n) y[(size_t)r * ND + o] = a2 + bb;
  r = r0 + lr + 6; if (r < n) y[(size_t)r * ND + o] = a3 + bb;
}

// out = (msg / (denom + 1e-8)) @ W + b
__global__ __launch_bounds__(256) void out_proj(const float* __restrict__ msg,
                                                const float* __restrict__ denom,
                                                const float* __restrict__ W,
                                                const float* __restrict__ b,
                                                float* __restrict__ y, int n) {
  __shared__ float xs[8][ND];
  const int r0 = blockIdx.x * 8;
  const int tid = threadIdx.x;
  const int lr = tid >> 7;
  const int o  = tid & 127;
  for (int i = tid; i < 8 * ND; i += 256) {
    int rr = i >> 7, cc = i & 127;
    int gr = r0 + rr;
    float v = 0.f;
    if (gr < n) {
      float dnm = denom[(size_t)gr * NH + (cc >> 4)];
      v = msg[(size_t)gr * ND + cc] / (dnm + 1e-8f);
    }
    xs[rr][cc] = v;
  }
  __syncthreads();
  float a0 = 0.f, a1 = 0.f, a2 = 0.f, a3 = 0.f;
#pragma unroll 8
  for (int k = 0; k < ND; ++k) {
    float w = W[k * ND + o];
    a0 = fmaf(xs[lr + 0][k], w, a0);
    a1 = fmaf(xs[lr + 2][k], w, a1);
    a2 = fmaf(xs[lr + 4][k], w, a2);
    a3 = fmaf(xs[lr + 6][k], w, a3);
  }
  const float bb = b[o];
  int r;
  r = r0 + lr + 0; if (r < n) y[(size_t)r * ND + o] = a0 + bb;
  r = r0 + lr + 2; if (r < n) y[(size_t)r * ND + o] = a1 + bb;
  r = r0 + lr + 4; if (r < n) y[(size_t)r * ND + o] = a2 + bb;
  r = r0 + lr + 6; if (r < n) y[(size_t)r * ND + o] = a3 + bb;
}

// One thread per (edge, head). h is derived from blockIdx only -> SGPR-uniform,
// so the `we` slice reads become scalar loads. Grid = 8 * (NE/256).
__global__ __launch_bounds__(256) void edge_pass(const int* __restrict__ ei,
                                                 const float* __restrict__ ea,
                                                 const float* __restrict__ Q,
                                                 const float* __restrict__ K,
                                                 const float* __restrict__ V,
                                                 const float* __restrict__ we,
                                                 const float* __restrict__ be,
                                                 float* __restrict__ msg,
                                                 float* __restrict__ denom) {
  const int EBLK = NE / 256;                    // 2500
  const int h = (int)blockIdx.x / EBLK;         // uniform across block
  const int e = ((int)blockIdx.x % EBLK) * 256 + (int)threadIdx.x;

  const int row = ei[e];
  const int col = ei[NE + e];

  const float4* qp4 = (const float4*)(Q + (size_t)row * ND + h * DKV);
  const float4* kp4 = (const float4*)(K + (size_t)col * ND + h * DKV);
  const float4* bep4 = (const float4*)(be + h * DKV);

  float q[DKV];
  float s = 0.f;
#pragma unroll
  for (int dq = 0; dq < 4; ++dq) {
    float4 qv = qp4[dq];
    float4 kv = kp4[dq];
    float4 bv = bep4[dq];
    q[dq * 4 + 0] = qv.x; q[dq * 4 + 1] = qv.y;
    q[dq * 4 + 2] = qv.z; q[dq * 4 + 3] = qv.w;
    s = fmaf(qv.x, kv.x + bv.x, s);   // Q·K + Q·be folded
    s = fmaf(qv.y, kv.y + bv.y, s);
    s = fmaf(qv.z, kv.z + bv.z, s);
    s = fmaf(qv.w, kv.w + bv.w, s);
  }

  // s += Q_h · (ea[e,:] @ we[:, h*16:(h+1)*16])
  const float4* ea4 = (const float4*)(ea + (size_t)e * ED);
  const float* wh = we + h * DKV;               // wh[j*ND + d]
  for (int j4 = 0; j4 < ED / 4; ++j4) {
    float4 a = ea4[j4];
    float p0 = 0.f, p1 = 0.f, p2 = 0.f, p3 = 0.f;
#pragma unroll
    for (int d = 0; d < DKV; ++d) {
      p0 = fmaf(q[d], wh[(j4 * 4 + 0) * ND + d], p0);
      p1 = fmaf(q[d], wh[(j4 * 4 + 1) * ND + d], p1);
      p2 = fmaf(q[d], wh[(j4 * 4 + 2) * ND + d], p2);
      p3 = fmaf(q[d], wh[(j4 * 4 + 3) * ND + d], p3);
    }
    s = fmaf(a.x, p0, s);
    s = fmaf(a.y, p1, s);
    s = fmaf(a.z, p2, s);
    s = fmaf(a.w, p3, s);
  }

  const float es = __expf(s * 0.25f);           // 1/sqrt(DK)=0.25

  atomicAdd(&denom[(size_t)row * NH + h], es);

  const float4* vp4 = (const float4*)(V + (size_t)col * ND + h * DKV);
  float* mp = msg + (size_t)row * ND + h * DKV;
#pragma unroll
  for (int dq = 0; dq < 4; ++dq) {
    float4 vv = vp4[dq];
    atomicAdd(&mp[dq * 4 + 0], es * vv.x);
    atomicAdd(&mp[dq * 4 + 1], es * vv.y);
    atomicAdd(&mp[dq * 4 + 2], es * vv.z);
    atomicAdd(&mp[dq * 4 + 3], es * vv.w);
  }
}

extern "C" void kernel_launch(void* const* d_in, const int* in_sizes, int n_in,
                              void* d_out, int out_size, void* d_ws, size_t ws_size,
                              hipStream_t stream) {
  const float* nodes = (const float*)d_in[0];
  const int*   ei    = (const int*)d_in[1];
  const float* ea    = (const float*)d_in[2];
  const float* wq    = (const float*)d_in[3];
  const float* bq    = (const float*)d_in[4];
  const float* wk    = (const float*)d_in[5];
  const float* bk    = (const float*)d_in[6];
  const float* wv    = (const float*)d_in[7];
  const float* bv    = (const float*)d_in[8];
  const float* we    = (const float*)d_in[9];
  const float* be    = (const float*)d_in[10];
  const float* wo    = (const float*)d_in[11];
  const float* bo    = (const float*)d_in[12];
  float* out = (float*)d_out;

  float* ws = (float*)d_ws;
  const size_t NND = (size_t)N_NODES * ND;
  float* Q     = ws;
  float* K     = Q + NND;
  float* V     = K + NND;
  float* msg   = V + NND;
  float* denom = msg + NND;

  // zero the accumulators (msg + denom are contiguous)
  hipMemsetAsync(msg, 0, (NND + (size_t)N_NODES * NH) * sizeof(float), stream);

  dim3 blk(256);
  dim3 gproj(N_NODES / 8);   // 40000 % 8 == 0
  proj128<<<gproj, blk, 0, stream>>>(nodes, wq, bq, Q, N_NODES);
  proj128<<<gproj, blk, 0, stream>>>(nodes, wk, bk, K, N_NODES);
  proj128<<<gproj, blk, 0, stream>>>(nodes, wv, bv, V, N_NODES);

  dim3 gedge(NH * (NE / 256));   // 8 * 2500 = 20000
  edge_pass<<<gedge, blk, 0, stream>>>(ei, ea, Q, K, V, we, be, msg, denom);

  out_proj<<<gproj, blk, 0, stream>>>(msg, denom, wo, bo, out, N_NODES);
}

// Round 2
// 519.531 us; speedup vs baseline: 9.1811x; 9.1811x over previous
//
#include <hip/hip_runtime.h>

#define NN  40000
#define NE  640000
#define ND  128
#define ED  64
#define NH  8
#define DK  16

#define SCAN_NBLK 157   // ceil(40000/256)

// ---------------- y = x @ W + b, x:[n,128] W:[128,128] ----------------
__global__ __launch_bounds__(256) void proj128(const float* __restrict__ x,
                                               const float* __restrict__ W,
                                               const float* __restrict__ b,
                                               float* __restrict__ y, int n) {
  __shared__ float xs[8][ND];
  const int r0 = blockIdx.x * 8;
  const int tid = threadIdx.x;
  const int lr = tid >> 7;
  const int o  = tid & 127;
  for (int i = tid; i < 8 * ND; i += 256) {
    int rr = i >> 7, cc = i & 127;
    int gr = r0 + rr;
    xs[rr][cc] = (gr < n) ? x[(size_t)gr * ND + cc] : 0.f;
  }
  __syncthreads();
  float a0 = 0.f, a1 = 0.f, a2 = 0.f, a3 = 0.f;
#pragma unroll 8
  for (int k = 0; k < ND; ++k) {
    float w = W[k * ND + o];
    a0 = fmaf(xs[lr + 0][k], w, a0);
    a1 = fmaf(xs[lr + 2][k], w, a1);
    a2 = fmaf(xs[lr + 4][k], w, a2);
    a3 = fmaf(xs[lr + 6][k], w, a3);
  }
  const float bb = b[o];
  int r;
  r = r0 + lr + 0; if (r < n) y[(size_t)r * ND + o] = a0 + bb;
  r = r0 + lr + 2; if (r < n) y[(size_t)r * ND + o] = a1 + bb;
  r = r0 + lr + 4; if (r < n) y[(size_t)r * ND + o] = a2 + bb;
  r = r0 + lr + 6; if (r < n) y[(size_t)r * ND + o] = a3 + bb;
}

// ---------------- CSR build ----------------
__global__ __launch_bounds__(256) void k_hist(const int* __restrict__ ei,
                                              int* __restrict__ hist) {
  int e = blockIdx.x * 256 + threadIdx.x;
  if (e < NE) atomicAdd(&hist[ei[e]], 1);
}

__global__ __launch_bounds__(256) void k_scan1(const int* __restrict__ hist,
                                               int* __restrict__ off,
                                               int* __restrict__ bsum) {
  __shared__ int sh[256];
  const int tid = threadIdx.x;
  const int idx = blockIdx.x * 256 + tid;
  int v = (idx < NN) ? hist[idx] : 0;
  sh[tid] = v;
  __syncthreads();
#pragma unroll
  for (int d = 1; d < 256; d <<= 1) {
    int t = (tid >= d) ? sh[tid - d] : 0;
    __syncthreads();
    sh[tid] += t;
    __syncthreads();
  }
  if (idx < NN) off[idx] = sh[tid] - v;       // exclusive
  if (tid == 255) bsum[blockIdx.x] = sh[255]; // block total
}

__global__ __launch_bounds__(256) void k_scan2(int* __restrict__ bsum) {
  __shared__ int sh[256];
  const int tid = threadIdx.x;
  int v = (tid < SCAN_NBLK) ? bsum[tid] : 0;
  sh[tid] = v;
  __syncthreads();
#pragma unroll
  for (int d = 1; d < 256; d <<= 1) {
    int t = (tid >= d) ? sh[tid - d] : 0;
    __syncthreads();
    sh[tid] += t;
    __syncthreads();
  }
  if (tid < SCAN_NBLK) bsum[tid] = sh[tid] - v; // exclusive
}

__global__ __launch_bounds__(256) void k_scan3(int* __restrict__ off,
                                               const int* __restrict__ bsum,
                                               int* __restrict__ cursor) {
  const int idx = blockIdx.x * 256 + threadIdx.x;
  if (idx < NN) {
    int o = off[idx] + bsum[blockIdx.x];
    off[idx] = o;
    cursor[idx] = o;
  }
  if (blockIdx.x == 0 && threadIdx.x == 0) off[NN] = NE;
}

__global__ __launch_bounds__(256) void k_scatter(const int* __restrict__ ei,
                                                 int* __restrict__ cursor,
                                                 int* __restrict__ colA,
                                                 int* __restrict__ eidA) {
  int e = blockIdx.x * 256 + threadIdx.x;
  if (e >= NE) return;
  int row = ei[e];
  int col = ei[NE + e];
  int pos = atomicAdd(&cursor[row], 1);
  colA[pos] = col;
  eidA[pos] = e;
}

// ---------------- fused per-(node,head) gather/softmax/aggregate ----------------
// thread t: n = t>>3, h = t&7  (8 head-threads of a node are adjacent lanes ->
// ea reads broadcast, Q/K/V reads cover full 512B lines)
__global__ __launch_bounds__(256) void k_gather(const float* __restrict__ Q,
                                                const float* __restrict__ K,
                                                const float* __restrict__ V,
                                                const float* __restrict__ we,
                                                const float* __restrict__ be,
                                                const float* __restrict__ ea,
                                                const int* __restrict__ off,
                                                const int* __restrict__ colA,
                                                const int* __restrict__ eidA,
                                                float* __restrict__ msgn) {
  const int t = blockIdx.x * 256 + threadIdx.x;  // grid exactly NN*NH threads
  const int n = t >> 3;
  const int h = t & 7;

  // Q fragment
  float q[DK];
  const float4* qp = (const float4*)(Q + (size_t)n * ND + h * DK);
#pragma unroll
  for (int i = 0; i < 4; ++i) {
    float4 v = qp[i];
    q[4 * i + 0] = v.x; q[4 * i + 1] = v.y; q[4 * i + 2] = v.z; q[4 * i + 3] = v.w;
  }

  // sbase = q · be_h
  float sbase = 0.f;
  const float4* bep = (const float4*)(be + h * DK);
#pragma unroll
  for (int i = 0; i < 4; ++i) {
    float4 b = bep[i];
    sbase = fmaf(q[4 * i + 0], b.x, sbase);
    sbase = fmaf(q[4 * i + 1], b.y, sbase);
    sbase = fmaf(q[4 * i + 2], b.z, sbase);
    sbase = fmaf(q[4 * i + 3], b.w, sbase);
  }

  // g[j] = q · we[j, h*16 : h*16+16]   (per-thread constant across edges)
  float g[ED];
  const float* wh = we + h * DK;
#pragma unroll
  for (int j = 0; j < ED; ++j) {
    const float4* wp = (const float4*)(wh + j * ND);
    float s = 0.f;
#pragma unroll
    for (int i = 0; i < 4; ++i) {
      float4 w = wp[i];
      s = fmaf(q[4 * i + 0], w.x, s);
      s = fmaf(q[4 * i + 1], w.y, s);
      s = fmaf(q[4 * i + 2], w.z, s);
      s = fmaf(q[4 * i + 3], w.w, s);
    }
    g[j] = s;
  }

  float acc[DK];
#pragma unroll
  for (int i = 0; i < DK; ++i) acc[i] = 0.f;
  float den = 0.f;

  const int j0 = off[n], j1 = off[n + 1];
  for (int j = j0; j < j1; ++j) {
    const int c = colA[j];
    const int e = eidA[j];

    float s = sbase;
    const float4* kp = (const float4*)(K + (size_t)c * ND + h * DK);
#pragma unroll
    for (int i = 0; i < 4; ++i) {
      float4 kv = kp[i];
      s = fmaf(q[4 * i + 0], kv.x, s);
      s = fmaf(q[4 * i + 1], kv.y, s);
      s = fmaf(q[4 * i + 2], kv.z, s);
      s = fmaf(q[4 * i + 3], kv.w, s);
    }

    const float4* ep = (const float4*)(ea + (size_t)e * ED);
#pragma unroll
    for (int j4 = 0; j4 < ED / 4; ++j4) {
      float4 a = ep[j4];
      s = fmaf(a.x, g[4 * j4 + 0], s);
      s = fmaf(a.y, g[4 * j4 + 1], s);
      s = fmaf(a.z, g[4 * j4 + 2], s);
      s = fmaf(a.w, g[4 * j4 + 3], s);
    }

    const float es = __expf(s * 0.25f);
    den += es;

    const float4* vp = (const float4*)(V + (size_t)c * ND + h * DK);
#pragma unroll
    for (int i = 0; i < 4; ++i) {
      float4 vv = vp[i];
      acc[4 * i + 0] = fmaf(es, vv.x, acc[4 * i + 0]);
      acc[4 * i + 1] = fmaf(es, vv.y, acc[4 * i + 1]);
      acc[4 * i + 2] = fmaf(es, vv.z, acc[4 * i + 2]);
      acc[4 * i + 3] = fmaf(es, vv.w, acc[4 * i + 3]);
    }
  }

  const float inv = 1.f / (den + 1e-8f);
  float4* mp = (float4*)(msgn + (size_t)n * ND + h * DK);
#pragma unroll
  for (int i = 0; i < 4; ++i) {
    float4 o;
    o.x = acc[4 * i + 0] * inv;
    o.y = acc[4 * i + 1] * inv;
    o.z = acc[4 * i + 2] * inv;
    o.w = acc[4 * i + 3] * inv;
    mp[i] = o;
  }
}

extern "C" void kernel_launch(void* const* d_in, const int* in_sizes, int n_in,
                              void* d_out, int out_size, void* d_ws, size_t ws_size,
                              hipStream_t stream) {
  const float* nodes = (const float*)d_in[0];
  const int*   ei    = (const int*)d_in[1];
  const float* ea    = (const float*)d_in[2];
  const float* wq    = (const float*)d_in[3];
  const float* bq    = (const float*)d_in[4];
  const float* wk    = (const float*)d_in[5];
  const float* bk    = (const float*)d_in[6];
  const float* wv    = (const float*)d_in[7];
  const float* bv    = (const float*)d_in[8];
  const float* we    = (const float*)d_in[9];
  const float* be    = (const float*)d_in[10];
  const float* wo    = (const float*)d_in[11];
  const float* bo    = (const float*)d_in[12];
  float* out = (float*)d_out;

  float* ws = (float*)d_ws;
  const size_t NND = (size_t)NN * ND;    // 5,120,000 floats
  float* Q    = ws;
  float* K    = Q + NND;
  float* V    = K + NND;
  float* msgn = V + NND;
  int* hist   = (int*)(msgn + NND);      // NN
  int* off    = hist + NN;               // NN+1 (padded to 40004)
  int* cursor = off + 40004;             // NN
  int* bsum   = cursor + NN;             // 256
  int* colA   = bsum + 256;              // NE
  int* eidA   = colA + NE;               // NE

  hipMemsetAsync(hist, 0, NN * sizeof(int), stream);

  dim3 blk(256);
  dim3 gproj(NN / 8);

  proj128<<<gproj, blk, 0, stream>>>(nodes, wq, bq, Q, NN);
  proj128<<<gproj, blk, 0, stream>>>(nodes, wk, bk, K, NN);
  proj128<<<gproj, blk, 0, stream>>>(nodes, wv, bv, V, NN);

  dim3 gE((NE + 255) / 256);
  k_hist<<<gE, blk, 0, stream>>>(ei, hist);
  k_scan1<<<dim3(SCAN_NBLK), blk, 0, stream>>>(hist, off, bsum);
  k_scan2<<<dim3(1), blk, 0, stream>>>(bsum);
  k_scan3<<<dim3(SCAN_NBLK), blk, 0, stream>>>(off, bsum, cursor);
  k_scatter<<<gE, blk, 0, stream>>>(ei, cursor, colA, eidA);

  dim3 gG((NN * NH) / 256);   // 1250
  k_gather<<<gG, blk, 0, stream>>>(Q, K, V, we, be, ea, off, colA, eidA, msgn);

  proj128<<<gproj, blk, 0, stream>>>(msgn, wo, bo, out, NN);
}

// Round 3
// 487.230 us; speedup vs baseline: 9.7898x; 1.0663x over previous
//
#include <hip/hip_runtime.h>

#define NN  40000
#define NE  640000
#define ND  128
#define ED  64
#define NH  8
#define DK  16

#define SCAN_NBLK 157   // ceil(40000/256)

// ---------------- fused Q/K/V projection ----------------
// block: 8 node rows, 256 threads. xs stored TRANSPOSED xs[k][r] so the
// k-loop reads one ds_read_b128 (4 rows) feeding 12 FMAs (3 matrices).
__global__ __launch_bounds__(256) void proj_qkv(const float* __restrict__ x,
                                                const float* __restrict__ wq,
                                                const float* __restrict__ bq,
                                                const float* __restrict__ wk,
                                                const float* __restrict__ bk,
                                                const float* __restrict__ wv,
                                                const float* __restrict__ bv,
                                                float* __restrict__ Q,
                                                float* __restrict__ K,
                                                float* __restrict__ V) {
  __shared__ float xs[ND][8];
  const int r0 = blockIdx.x * 8;
  const int tid = threadIdx.x;
  for (int i = tid; i < 8 * ND; i += 256) {
    int r = i >> 7, c = i & 127;
    xs[c][r] = x[(size_t)(r0 + r) * ND + c];
  }
  __syncthreads();

  const int o = tid & 127;
  const int half = tid >> 7;           // rows half*4 .. half*4+3
  float aq0 = 0.f, aq1 = 0.f, aq2 = 0.f, aq3 = 0.f;
  float ak0 = 0.f, ak1 = 0.f, ak2 = 0.f, ak3 = 0.f;
  float av0 = 0.f, av1 = 0.f, av2 = 0.f, av3 = 0.f;
#pragma unroll 4
  for (int k = 0; k < ND; ++k) {
    float4 xv = *(const float4*)&xs[k][half * 4];
    float wqv = wq[k * ND + o];
    float wkv = wk[k * ND + o];
    float wvv = wv[k * ND + o];
    aq0 = fmaf(xv.x, wqv, aq0); aq1 = fmaf(xv.y, wqv, aq1);
    aq2 = fmaf(xv.z, wqv, aq2); aq3 = fmaf(xv.w, wqv, aq3);
    ak0 = fmaf(xv.x, wkv, ak0); ak1 = fmaf(xv.y, wkv, ak1);
    ak2 = fmaf(xv.z, wkv, ak2); ak3 = fmaf(xv.w, wkv, ak3);
    av0 = fmaf(xv.x, wvv, av0); av1 = fmaf(xv.y, wvv, av1);
    av2 = fmaf(xv.z, wvv, av2); av3 = fmaf(xv.w, wvv, av3);
  }
  const float bqv = bq[o], bkv = bk[o], bvv = bv[o];
  const size_t base = (size_t)(r0 + half * 4) * ND + o;
  Q[base + 0 * ND] = aq0 + bqv; Q[base + 1 * ND] = aq1 + bqv;
  Q[base + 2 * ND] = aq2 + bqv; Q[base + 3 * ND] = aq3 + bqv;
  K[base + 0 * ND] = ak0 + bkv; K[base + 1 * ND] = ak1 + bkv;
  K[base + 2 * ND] = ak2 + bkv; K[base + 3 * ND] = ak3 + bkv;
  V[base + 0 * ND] = av0 + bvv; V[base + 1 * ND] = av1 + bvv;
  V[base + 2 * ND] = av2 + bvv; V[base + 3 * ND] = av3 + bvv;
}

// ---------------- out = (msgn) @ W + b ----------------
__global__ __launch_bounds__(256) void proj128(const float* __restrict__ x,
                                               const float* __restrict__ W,
                                               const float* __restrict__ b,
                                               float* __restrict__ y) {
  __shared__ float xs[ND][8];
  const int r0 = blockIdx.x * 8;
  const int tid = threadIdx.x;
  for (int i = tid; i < 8 * ND; i += 256) {
    int r = i >> 7, c = i & 127;
    xs[c][r] = x[(size_t)(r0 + r) * ND + c];
  }
  __syncthreads();
  const int o = tid & 127;
  const int half = tid >> 7;
  float a0 = 0.f, a1 = 0.f, a2 = 0.f, a3 = 0.f;
#pragma unroll 8
  for (int k = 0; k < ND; ++k) {
    float4 xv = *(const float4*)&xs[k][half * 4];
    float w = W[k * ND + o];
    a0 = fmaf(xv.x, w, a0); a1 = fmaf(xv.y, w, a1);
    a2 = fmaf(xv.z, w, a2); a3 = fmaf(xv.w, w, a3);
  }
  const float bb = b[o];
  const size_t base = (size_t)(r0 + half * 4) * ND + o;
  y[base + 0 * ND] = a0 + bb; y[base + 1 * ND] = a1 + bb;
  y[base + 2 * ND] = a2 + bb; y[base + 3 * ND] = a3 + bb;
}

// ---------------- CSR build ----------------
__global__ __launch_bounds__(256) void k_hist(const int* __restrict__ ei,
                                              int* __restrict__ hist) {
  int e = blockIdx.x * 256 + threadIdx.x;
  if (e < NE) atomicAdd(&hist[ei[e]], 1);
}

__global__ __launch_bounds__(256) void k_scan1(const int* __restrict__ hist,
                                               int* __restrict__ off,
                                               int* __restrict__ bsum) {
  __shared__ int sh[256];
  const int tid = threadIdx.x;
  const int idx = blockIdx.x * 256 + tid;
  int v = (idx < NN) ? hist[idx] : 0;
  sh[tid] = v;
  __syncthreads();
#pragma unroll
  for (int d = 1; d < 256; d <<= 1) {
    int t = (tid >= d) ? sh[tid - d] : 0;
    __syncthreads();
    sh[tid] += t;
    __syncthreads();
  }
  if (idx < NN) off[idx] = sh[tid] - v;
  if (tid == 255) bsum[blockIdx.x] = sh[255];
}

__global__ __launch_bounds__(256) void k_scan2(int* __restrict__ bsum) {
  __shared__ int sh[256];
  const int tid = threadIdx.x;
  int v = (tid < SCAN_NBLK) ? bsum[tid] : 0;
  sh[tid] = v;
  __syncthreads();
#pragma unroll
  for (int d = 1; d < 256; d <<= 1) {
    int t = (tid >= d) ? sh[tid - d] : 0;
    __syncthreads();
    sh[tid] += t;
    __syncthreads();
  }
  if (tid < SCAN_NBLK) bsum[tid] = sh[tid] - v;
}

__global__ __launch_bounds__(256) void k_scan3(int* __restrict__ off,
                                               const int* __restrict__ bsum,
                                               int* __restrict__ cursor) {
  const int idx = blockIdx.x * 256 + threadIdx.x;
  if (idx < NN) {
    int o = off[idx] + bsum[blockIdx.x];
    off[idx] = o;
    cursor[idx] = o;
  }
  if (blockIdx.x == 0 && threadIdx.x == 0) off[NN] = NE;
}

__global__ __launch_bounds__(256) void k_scatter(const int* __restrict__ ei,
                                                 int* __restrict__ cursor,
                                                 int* __restrict__ colA,
                                                 int* __restrict__ eidA) {
  int e = blockIdx.x * 256 + threadIdx.x;
  if (e >= NE) return;
  int row = ei[e];
  int col = ei[NE + e];
  int pos = atomicAdd(&cursor[row], 1);
  colA[pos] = col;
  eidA[pos] = e;
}

// ---------------- fused gather: 32 lanes per node ----------------
// lane l = (h<<2)|q : h=head, q=quarter. q owns DK-slice [q*4,q*4+4) and
// ea/G-slice [q*16,q*16+16). Score finished by shfl_xor over the q-group.
__global__ __launch_bounds__(256) void k_gather(const float* __restrict__ Q,
                                                const float* __restrict__ K,
                                                const float* __restrict__ V,
                                                const float* __restrict__ we,
                                                const float* __restrict__ be,
                                                const float* __restrict__ ea,
                                                const int* __restrict__ off,
                                                const int* __restrict__ colA,
                                                const int* __restrict__ eidA,
                                                float* __restrict__ msgn) {
  const int n = blockIdx.x * 8 + (threadIdx.x >> 5);
  const int l = threadIdx.x & 31;
  const int h = l >> 2;
  const int q = l & 3;

  // full Q head-slice for setup
  float qf[DK];
  {
    const float4* qp = (const float4*)(Q + (size_t)n * ND + h * DK);
#pragma unroll
    for (int i = 0; i < 4; ++i) {
      float4 v = qp[i];
      qf[4 * i + 0] = v.x; qf[4 * i + 1] = v.y;
      qf[4 * i + 2] = v.z; qf[4 * i + 3] = v.w;
    }
  }

  // sbase = full q·be_h (per lane)
  float sbase = 0.f;
  {
    const float4* bp = (const float4*)(be + h * DK);
#pragma unroll
    for (int i = 0; i < 4; ++i) {
      float4 b = bp[i];
      sbase = fmaf(qf[4 * i + 0], b.x, sbase);
      sbase = fmaf(qf[4 * i + 1], b.y, sbase);
      sbase = fmaf(qf[4 * i + 2], b.z, sbase);
      sbase = fmaf(qf[4 * i + 3], b.w, sbase);
    }
  }

  // g[jj] = q · we[q*16+jj, h*16 .. +16)   (16 j's per lane)
  float g[16];
#pragma unroll
  for (int jj = 0; jj < 16; ++jj) {
    const float4* wp = (const float4*)(we + (size_t)(q * 16 + jj) * ND + h * DK);
    float s = 0.f;
#pragma unroll
    for (int i = 0; i < 4; ++i) {
      float4 w = wp[i];
      s = fmaf(qf[4 * i + 0], w.x, s);
      s = fmaf(qf[4 * i + 1], w.y, s);
      s = fmaf(qf[4 * i + 2], w.z, s);
      s = fmaf(qf[4 * i + 3], w.w, s);
    }
    g[jj] = s;
  }

  // keep only our DK quarter of q
  float4 qv;
  qv.x = qf[q * 4 + 0]; qv.y = qf[q * 4 + 1];
  qv.z = qf[q * 4 + 2]; qv.w = qf[q * 4 + 3];

  float4 acc = make_float4(0.f, 0.f, 0.f, 0.f);
  float den = 0.f;

  const int j0 = off[n], j1 = off[n + 1];
  for (int jp = j0; jp < j1; ++jp) {
    const int c = colA[jp];
    const int e = eidA[jp];

    // partial score: QK over our d-quarter
    float p;
    {
      float4 kv = *(const float4*)(K + (size_t)c * ND + h * DK + q * 4);
      p = qv.x * kv.x;
      p = fmaf(qv.y, kv.y, p);
      p = fmaf(qv.z, kv.z, p);
      p = fmaf(qv.w, kv.w, p);
    }
    // + ea·g over our 16-wide ea-slice
    {
      const float4* ep = (const float4*)(ea + (size_t)e * ED + q * 16);
#pragma unroll
      for (int i = 0; i < 4; ++i) {
        float4 a = ep[i];
        p = fmaf(a.x, g[4 * i + 0], p);
        p = fmaf(a.y, g[4 * i + 1], p);
        p = fmaf(a.z, g[4 * i + 2], p);
        p = fmaf(a.w, g[4 * i + 3], p);
      }
    }
    // reduce across the 4 q-lanes
    p += __shfl_xor(p, 1);
    p += __shfl_xor(p, 2);

    const float es = __expf((p + sbase) * 0.25f);
    den += es;

    float4 vv = *(const float4*)(V + (size_t)c * ND + h * DK + q * 4);
    acc.x = fmaf(es, vv.x, acc.x);
    acc.y = fmaf(es, vv.y, acc.y);
    acc.z = fmaf(es, vv.z, acc.z);
    acc.w = fmaf(es, vv.w, acc.w);
  }

  const float inv = 1.f / (den + 1e-8f);
  float4 o;
  o.x = acc.x * inv; o.y = acc.y * inv; o.z = acc.z * inv; o.w = acc.w * inv;
  *(float4*)(msgn + (size_t)n * ND + h * DK + q * 4) = o;
}

extern "C" void kernel_launch(void* const* d_in, const int* in_sizes, int n_in,
                              void* d_out, int out_size, void* d_ws, size_t ws_size,
                              hipStream_t stream) {
  const float* nodes = (const float*)d_in[0];
  const int*   ei    = (const int*)d_in[1];
  const float* ea    = (const float*)d_in[2];
  const float* wq    = (const float*)d_in[3];
  const float* bq    = (const float*)d_in[4];
  const float* wk    = (const float*)d_in[5];
  const float* bk    = (const float*)d_in[6];
  const float* wv    = (const float*)d_in[7];
  const float* bv    = (const float*)d_in[8];
  const float* we    = (const float*)d_in[9];
  const float* be    = (const float*)d_in[10];
  const float* wo    = (const float*)d_in[11];
  const float* bo    = (const float*)d_in[12];
  float* out = (float*)d_out;

  float* ws = (float*)d_ws;
  const size_t NND = (size_t)NN * ND;
  float* Q    = ws;
  float* K    = Q + NND;
  float* V    = K + NND;
  float* msgn = V + NND;
  int* hist   = (int*)(msgn + NND);
  int* off    = hist + NN;
  int* cursor = off + 40004;
  int* bsum   = cursor + NN;
  int* colA   = bsum + 256;
  int* eidA   = colA + NE;

  hipMemsetAsync(hist, 0, NN * sizeof(int), stream);

  dim3 blk(256);
  dim3 gproj(NN / 8);

  proj_qkv<<<gproj, blk, 0, stream>>>(nodes, wq, bq, wk, bk, wv, bv, Q, K, V);

  dim3 gE((NE + 255) / 256);
  k_hist<<<gE, blk, 0, stream>>>(ei, hist);
  k_scan1<<<dim3(SCAN_NBLK), blk, 0, stream>>>(hist, off, bsum);
  k_scan2<<<dim3(1), blk, 0, stream>>>(bsum);
  k_scan3<<<dim3(SCAN_NBLK), blk, 0, stream>>>(off, bsum, cursor);
  k_scatter<<<gE, blk, 0, stream>>>(ei, cursor, colA, eidA);

  dim3 gG(NN / 8);   // 5000 blocks, 32 lanes per node
  k_gather<<<gG, blk, 0, stream>>>(Q, K, V, we, be, ea, off, colA, eidA, msgn);

  proj128<<<gproj, blk, 0, stream>>>(msgn, wo, bo, out);
}

// Round 4
// 463.703 us; speedup vs baseline: 10.2865x; 1.0507x over previous
//
#include <hip/hip_runtime.h>

#define NN  40000
#define NE  640000
#define ND  128
#define ED  64
#define NH  8
#define DK  16

#define SCAN_NBLK 157   // ceil(40000/256)

// ---------------- fused Q/K/V projection ----------------
__global__ __launch_bounds__(256) void proj_qkv(const float* __restrict__ x,
                                                const float* __restrict__ wq,
                                                const float* __restrict__ bq,
                                                const float* __restrict__ wk,
                                                const float* __restrict__ bk,
                                                const float* __restrict__ wv,
                                                const float* __restrict__ bv,
                                                float* __restrict__ Q,
                                                float* __restrict__ K,
                                                float* __restrict__ V) {
  __shared__ float xs[ND][8];
  const int r0 = blockIdx.x * 8;
  const int tid = threadIdx.x;
  for (int i = tid; i < 8 * ND; i += 256) {
    int r = i >> 7, c = i & 127;
    xs[c][r] = x[(size_t)(r0 + r) * ND + c];
  }
  __syncthreads();

  const int o = tid & 127;
  const int half = tid >> 7;
  float aq0 = 0.f, aq1 = 0.f, aq2 = 0.f, aq3 = 0.f;
  float ak0 = 0.f, ak1 = 0.f, ak2 = 0.f, ak3 = 0.f;
  float av0 = 0.f, av1 = 0.f, av2 = 0.f, av3 = 0.f;
#pragma unroll 4
  for (int k = 0; k < ND; ++k) {
    float4 xv = *(const float4*)&xs[k][half * 4];
    float wqv = wq[k * ND + o];
    float wkv = wk[k * ND + o];
    float wvv = wv[k * ND + o];
    aq0 = fmaf(xv.x, wqv, aq0); aq1 = fmaf(xv.y, wqv, aq1);
    aq2 = fmaf(xv.z, wqv, aq2); aq3 = fmaf(xv.w, wqv, aq3);
    ak0 = fmaf(xv.x, wkv, ak0); ak1 = fmaf(xv.y, wkv, ak1);
    ak2 = fmaf(xv.z, wkv, ak2); ak3 = fmaf(xv.w, wkv, ak3);
    av0 = fmaf(xv.x, wvv, av0); av1 = fmaf(xv.y, wvv, av1);
    av2 = fmaf(xv.z, wvv, av2); av3 = fmaf(xv.w, wvv, av3);
  }
  const float bqv = bq[o], bkv = bk[o], bvv = bv[o];
  const size_t base = (size_t)(r0 + half * 4) * ND + o;
  Q[base + 0 * ND] = aq0 + bqv; Q[base + 1 * ND] = aq1 + bqv;
  Q[base + 2 * ND] = aq2 + bqv; Q[base + 3 * ND] = aq3 + bqv;
  K[base + 0 * ND] = ak0 + bkv; K[base + 1 * ND] = ak1 + bkv;
  K[base + 2 * ND] = ak2 + bkv; K[base + 3 * ND] = ak3 + bkv;
  V[base + 0 * ND] = av0 + bvv; V[base + 1 * ND] = av1 + bvv;
  V[base + 2 * ND] = av2 + bvv; V[base + 3 * ND] = av3 + bvv;
}

// ---------------- out = msgn @ W + b ----------------
__global__ __launch_bounds__(256) void proj128(const float* __restrict__ x,
                                               const float* __restrict__ W,
                                               const float* __restrict__ b,
                                               float* __restrict__ y) {
  __shared__ float xs[ND][8];
  const int r0 = blockIdx.x * 8;
  const int tid = threadIdx.x;
  for (int i = tid; i < 8 * ND; i += 256) {
    int r = i >> 7, c = i & 127;
    xs[c][r] = x[(size_t)(r0 + r) * ND + c];
  }
  __syncthreads();
  const int o = tid & 127;
  const int half = tid >> 7;
  float a0 = 0.f, a1 = 0.f, a2 = 0.f, a3 = 0.f;
#pragma unroll 8
  for (int k = 0; k < ND; ++k) {
    float4 xv = *(const float4*)&xs[k][half * 4];
    float w = W[k * ND + o];
    a0 = fmaf(xv.x, w, a0); a1 = fmaf(xv.y, w, a1);
    a2 = fmaf(xv.z, w, a2); a3 = fmaf(xv.w, w, a3);
  }
  const float bb = b[o];
  const size_t base = (size_t)(r0 + half * 4) * ND + o;
  y[base + 0 * ND] = a0 + bb; y[base + 1 * ND] = a1 + bb;
  y[base + 2 * ND] = a2 + bb; y[base + 3 * ND] = a3 + bb;
}

// ---------------- CSR build ----------------
__global__ __launch_bounds__(256) void k_hist(const int* __restrict__ ei,
                                              int* __restrict__ hist) {
  int e = blockIdx.x * 256 + threadIdx.x;
  if (e < NE) atomicAdd(&hist[ei[e]], 1);
}

__global__ __launch_bounds__(256) void k_scan1(const int* __restrict__ hist,
                                               int* __restrict__ off,
                                               int* __restrict__ bsum) {
  __shared__ int sh[256];
  const int tid = threadIdx.x;
  const int idx = blockIdx.x * 256 + tid;
  int v = (idx < NN) ? hist[idx] : 0;
  sh[tid] = v;
  __syncthreads();
#pragma unroll
  for (int d = 1; d < 256; d <<= 1) {
    int t = (tid >= d) ? sh[tid - d] : 0;
    __syncthreads();
    sh[tid] += t;
    __syncthreads();
  }
  if (idx < NN) off[idx] = sh[tid] - v;
  if (tid == 255) bsum[blockIdx.x] = sh[255];
}

__global__ __launch_bounds__(256) void k_scan2(int* __restrict__ bsum) {
  __shared__ int sh[256];
  const int tid = threadIdx.x;
  int v = (tid < SCAN_NBLK) ? bsum[tid] : 0;
  sh[tid] = v;
  __syncthreads();
#pragma unroll
  for (int d = 1; d < 256; d <<= 1) {
    int t = (tid >= d) ? sh[tid - d] : 0;
    __syncthreads();
    sh[tid] += t;
    __syncthreads();
  }
  if (tid < SCAN_NBLK) bsum[tid] = sh[tid] - v;
}

__global__ __launch_bounds__(256) void k_scan3(int* __restrict__ off,
                                               const int* __restrict__ bsum,
                                               int* __restrict__ cursor) {
  const int idx = blockIdx.x * 256 + threadIdx.x;
  if (idx < NN) {
    int o = off[idx] + bsum[blockIdx.x];
    off[idx] = o;
    cursor[idx] = o;
  }
  if (blockIdx.x == 0 && threadIdx.x == 0) off[NN] = NE;
}

__global__ __launch_bounds__(256) void k_scatter(const int* __restrict__ ei,
                                                 int* __restrict__ cursor,
                                                 int2* __restrict__ pair) {
  int e = blockIdx.x * 256 + threadIdx.x;
  if (e >= NE) return;
  int row = ei[e];
  int col = ei[NE + e];
  int pos = atomicAdd(&cursor[row], 1);
  pair[pos] = make_int2(col, e);
}

// ---------------- fused gather: 32 lanes per node, 4 edges in flight ----------------
// lane l = (h<<2)|q : h=head, q=quarter. q owns DK-slice [q*4,q*4+4) and
// ea/G-slice [q*16,q*16+16). Score finished by shfl_xor over the q-group.
__global__ __launch_bounds__(256) void k_gather(const float* __restrict__ Q,
                                                const float* __restrict__ K,
                                                const float* __restrict__ V,
                                                const float* __restrict__ we,
                                                const float* __restrict__ be,
                                                const float* __restrict__ ea,
                                                const int* __restrict__ off,
                                                const int2* __restrict__ pair,
                                                float* __restrict__ msgn) {
  const int n = blockIdx.x * 8 + (threadIdx.x >> 5);
  const int l = threadIdx.x & 31;
  const int h = l >> 2;
  const int q = l & 3;

  float qf[DK];
  {
    const float4* qp = (const float4*)(Q + (size_t)n * ND + h * DK);
#pragma unroll
    for (int i = 0; i < 4; ++i) {
      float4 v = qp[i];
      qf[4 * i + 0] = v.x; qf[4 * i + 1] = v.y;
      qf[4 * i + 2] = v.z; qf[4 * i + 3] = v.w;
    }
  }

  float sbase = 0.f;
  {
    const float4* bp = (const float4*)(be + h * DK);
#pragma unroll
    for (int i = 0; i < 4; ++i) {
      float4 b = bp[i];
      sbase = fmaf(qf[4 * i + 0], b.x, sbase);
      sbase = fmaf(qf[4 * i + 1], b.y, sbase);
      sbase = fmaf(qf[4 * i + 2], b.z, sbase);
      sbase = fmaf(qf[4 * i + 3], b.w, sbase);
    }
  }
  const float sb = sbase * 0.25f;   // pre-scaled bias term

  float g[16];
#pragma unroll
  for (int jj = 0; jj < 16; ++jj) {
    const float4* wp = (const float4*)(we + (size_t)(q * 16 + jj) * ND + h * DK);
    float s = 0.f;
#pragma unroll
    for (int i = 0; i < 4; ++i) {
      float4 w = wp[i];
      s = fmaf(qf[4 * i + 0], w.x, s);
      s = fmaf(qf[4 * i + 1], w.y, s);
      s = fmaf(qf[4 * i + 2], w.z, s);
      s = fmaf(qf[4 * i + 3], w.w, s);
    }
    g[jj] = s;
  }

  float4 qv;
  qv.x = qf[q * 4 + 0]; qv.y = qf[q * 4 + 1];
  qv.z = qf[q * 4 + 2]; qv.w = qf[q * 4 + 3];

  float4 acc = make_float4(0.f, 0.f, 0.f, 0.f);
  float den = 0.f;

  const int j0 = off[n], j1 = off[n + 1];
  const int hq = h * DK + q * 4;
  int jp = j0;

  for (; jp + 4 <= j1; jp += 4) {
    const int2 p0 = pair[jp + 0];
    const int2 p1 = pair[jp + 1];
    const int2 p2 = pair[jp + 2];
    const int2 p3 = pair[jp + 3];

    // all K loads issued together
    const float4 k0 = *(const float4*)(K + (size_t)p0.x * ND + hq);
    const float4 k1 = *(const float4*)(K + (size_t)p1.x * ND + hq);
    const float4 k2 = *(const float4*)(K + (size_t)p2.x * ND + hq);
    const float4 k3 = *(const float4*)(K + (size_t)p3.x * ND + hq);

    const float4* e0 = (const float4*)(ea + (size_t)p0.y * ED + q * 16);
    const float4* e1 = (const float4*)(ea + (size_t)p1.y * ED + q * 16);
    const float4* e2 = (const float4*)(ea + (size_t)p2.y * ED + q * 16);
    const float4* e3 = (const float4*)(ea + (size_t)p3.y * ED + q * 16);

    float s0 = k0.x * qv.x; s0 = fmaf(qv.y, k0.y, s0); s0 = fmaf(qv.z, k0.z, s0); s0 = fmaf(qv.w, k0.w, s0);
    float s1 = k1.x * qv.x; s1 = fmaf(qv.y, k1.y, s1); s1 = fmaf(qv.z, k1.z, s1); s1 = fmaf(qv.w, k1.w, s1);
    float s2 = k2.x * qv.x; s2 = fmaf(qv.y, k2.y, s2); s2 = fmaf(qv.z, k2.z, s2); s2 = fmaf(qv.w, k2.w, s2);
    float s3 = k3.x * qv.x; s3 = fmaf(qv.y, k3.y, s3); s3 = fmaf(qv.z, k3.z, s3); s3 = fmaf(qv.w, k3.w, s3);

#pragma unroll
    for (int i = 0; i < 4; ++i) {
      float4 a0 = e0[i];
      s0 = fmaf(a0.x, g[4 * i + 0], s0); s0 = fmaf(a0.y, g[4 * i + 1], s0);
      s0 = fmaf(a0.z, g[4 * i + 2], s0); s0 = fmaf(a0.w, g[4 * i + 3], s0);
    }
#pragma unroll
    for (int i = 0; i < 4; ++i) {
      float4 a1 = e1[i];
      s1 = fmaf(a1.x, g[4 * i + 0], s1); s1 = fmaf(a1.y, g[4 * i + 1], s1);
      s1 = fmaf(a1.z, g[4 * i + 2], s1); s1 = fmaf(a1.w, g[4 * i + 3], s1);
    }
#pragma unroll
    for (int i = 0; i < 4; ++i) {
      float4 a2 = e2[i];
      s2 = fmaf(a2.x, g[4 * i + 0], s2); s2 = fmaf(a2.y, g[4 * i + 1], s2);
      s2 = fmaf(a2.z, g[4 * i + 2], s2); s2 = fmaf(a2.w, g[4 * i + 3], s2);
    }
#pragma unroll
    for (int i = 0; i < 4; ++i) {
      float4 a3 = e3[i];
      s3 = fmaf(a3.x, g[4 * i + 0], s3); s3 = fmaf(a3.y, g[4 * i + 1], s3);
      s3 = fmaf(a3.z, g[4 * i + 2], s3); s3 = fmaf(a3.w, g[4 * i + 3], s3);
    }

    s0 += __shfl_xor(s0, 1); s0 += __shfl_xor(s0, 2);
    s1 += __shfl_xor(s1, 1); s1 += __shfl_xor(s1, 2);
    s2 += __shfl_xor(s2, 1); s2 += __shfl_xor(s2, 2);
    s3 += __shfl_xor(s3, 1); s3 += __shfl_xor(s3, 2);

    const float es0 = __expf(fmaf(s0, 0.25f, sb));
    const float es1 = __expf(fmaf(s1, 0.25f, sb));
    const float es2 = __expf(fmaf(s2, 0.25f, sb));
    const float es3 = __expf(fmaf(s3, 0.25f, sb));
    den += (es0 + es1) + (es2 + es3);

    const float4 v0 = *(const float4*)(V + (size_t)p0.x * ND + hq);
    const float4 v1 = *(const float4*)(V + (size_t)p1.x * ND + hq);
    const float4 v2 = *(const float4*)(V + (size_t)p2.x * ND + hq);
    const float4 v3 = *(const float4*)(V + (size_t)p3.x * ND + hq);

    acc.x = fmaf(es0, v0.x, acc.x); acc.y = fmaf(es0, v0.y, acc.y);
    acc.z = fmaf(es0, v0.z, acc.z); acc.w = fmaf(es0, v0.w, acc.w);
    acc.x = fmaf(es1, v1.x, acc.x); acc.y = fmaf(es1, v1.y, acc.y);
    acc.z = fmaf(es1, v1.z, acc.z); acc.w = fmaf(es1, v1.w, acc.w);
    acc.x = fmaf(es2, v2.x, acc.x); acc.y = fmaf(es2, v2.y, acc.y);
    acc.z = fmaf(es2, v2.z, acc.z); acc.w = fmaf(es2, v2.w, acc.w);
    acc.x = fmaf(es3, v3.x, acc.x); acc.y = fmaf(es3, v3.y, acc.y);
    acc.z = fmaf(es3, v3.z, acc.z); acc.w = fmaf(es3, v3.w, acc.w);
  }

  for (; jp < j1; ++jp) {
    const int2 p = pair[jp];
    const float4 kv = *(const float4*)(K + (size_t)p.x * ND + hq);
    float s = kv.x * qv.x;
    s = fmaf(qv.y, kv.y, s); s = fmaf(qv.z, kv.z, s); s = fmaf(qv.w, kv.w, s);
    const float4* ep = (const float4*)(ea + (size_t)p.y * ED + q * 16);
#pragma unroll
    for (int i = 0; i < 4; ++i) {
      float4 a = ep[i];
      s = fmaf(a.x, g[4 * i + 0], s); s = fmaf(a.y, g[4 * i + 1], s);
      s = fmaf(a.z, g[4 * i + 2], s); s = fmaf(a.w, g[4 * i + 3], s);
    }
    s += __shfl_xor(s, 1); s += __shfl_xor(s, 2);
    const float es = __expf(fmaf(s, 0.25f, sb));
    den += es;
    const float4 vv = *(const float4*)(V + (size_t)p.x * ND + hq);
    acc.x = fmaf(es, vv.x, acc.x); acc.y = fmaf(es, vv.y, acc.y);
    acc.z = fmaf(es, vv.z, acc.z); acc.w = fmaf(es, vv.w, acc.w);
  }

  const float inv = 1.f / (den + 1e-8f);
  float4 o;
  o.x = acc.x * inv; o.y = acc.y * inv; o.z = acc.z * inv; o.w = acc.w * inv;
  *(float4*)(msgn + (size_t)n * ND + h * DK + q * 4) = o;
}

extern "C" void kernel_launch(void* const* d_in, const int* in_sizes, int n_in,
                              void* d_out, int out_size, void* d_ws, size_t ws_size,
                              hipStream_t stream) {
  const float* nodes = (const float*)d_in[0];
  const int*   ei    = (const int*)d_in[1];
  const float* ea    = (const float*)d_in[2];
  const float* wq    = (const float*)d_in[3];
  const float* bq    = (const float*)d_in[4];
  const float* wk    = (const float*)d_in[5];
  const float* bk    = (const float*)d_in[6];
  const float* wv    = (const float*)d_in[7];
  const float* bv    = (const float*)d_in[8];
  const float* we    = (const float*)d_in[9];
  const float* be    = (const float*)d_in[10];
  const float* wo    = (const float*)d_in[11];
  const float* bo    = (const float*)d_in[12];
  float* out = (float*)d_out;

  float* ws = (float*)d_ws;
  const size_t NND = (size_t)NN * ND;
  float* Q    = ws;
  float* K    = Q + NND;
  float* V    = K + NND;
  float* msgn = V + NND;
  int* hist   = (int*)(msgn + NND);
  int* off    = hist + NN;            // NN+1 (padded to 40004)
  int* cursor = off + 40004;
  int* bsum   = cursor + NN;
  int2* pair  = (int2*)(bsum + 256);  // NE int2 (8B-aligned: offset is even)

  hipMemsetAsync(hist, 0, NN * sizeof(int), stream);

  dim3 blk(256);
  dim3 gproj(NN / 8);

  proj_qkv<<<gproj, blk, 0, stream>>>(nodes, wq, bq, wk, bk, wv, bv, Q, K, V);

  dim3 gE((NE + 255) / 256);
  k_hist<<<gE, blk, 0, stream>>>(ei, hist);
  k_scan1<<<dim3(SCAN_NBLK), blk, 0, stream>>>(hist, off, bsum);
  k_scan2<<<dim3(1), blk, 0, stream>>>(bsum);
  k_scan3<<<dim3(SCAN_NBLK), blk, 0, stream>>>(off, bsum, cursor);
  k_scatter<<<gE, blk, 0, stream>>>(ei, cursor, pair);

  dim3 gG(NN / 8);
  k_gather<<<gG, blk, 0, stream>>>(Q, K, V, we, be, ea, off, pair, msgn);

  proj128<<<gproj, blk, 0, stream>>>(msgn, wo, bo, out);
}

// Round 5
// 367.723 us; speedup vs baseline: 12.9714x; 1.2610x over previous
//
#include <hip/hip_runtime.h>

#define NN  40000
#define NE  640000
#define ND  128
#define ED  64
#define NH  8
#define DK  16

#define SCAN_NBLK 157   // ceil(40000/256)

// ---------------- fused Q/K/V projection: 16 rows/block ----------------
__global__ __launch_bounds__(256) void proj_qkv(const float* __restrict__ x,
                                                const float* __restrict__ wq,
                                                const float* __restrict__ bq,
                                                const float* __restrict__ wk,
                                                const float* __restrict__ bk,
                                                const float* __restrict__ wv,
                                                const float* __restrict__ bv,
                                                float* __restrict__ Q,
                                                float* __restrict__ K,
                                                float* __restrict__ V) {
  __shared__ float xs[ND][20];   // pad 20: float4-aligned rows, 8-way write conflicts max
  const int r0 = blockIdx.x * 16;
  const int tid = threadIdx.x;
  for (int i = tid; i < 16 * ND; i += 256) {
    int r = i >> 7, c = i & 127;
    xs[c][r] = x[(size_t)(r0 + r) * ND + c];
  }
  __syncthreads();

  const int o = tid & 127;
  const int half = tid >> 7;        // rows half*8 .. half*8+7
  float aq[8], ak[8], av[8];
#pragma unroll
  for (int j = 0; j < 8; ++j) { aq[j] = 0.f; ak[j] = 0.f; av[j] = 0.f; }

#pragma unroll 4
  for (int k = 0; k < ND; ++k) {
    float4 xa = *(const float4*)&xs[k][half * 8];
    float4 xb = *(const float4*)&xs[k][half * 8 + 4];
    float wqv = wq[k * ND + o];
    float wkv = wk[k * ND + o];
    float wvv = wv[k * ND + o];
    aq[0] = fmaf(xa.x, wqv, aq[0]); aq[1] = fmaf(xa.y, wqv, aq[1]);
    aq[2] = fmaf(xa.z, wqv, aq[2]); aq[3] = fmaf(xa.w, wqv, aq[3]);
    aq[4] = fmaf(xb.x, wqv, aq[4]); aq[5] = fmaf(xb.y, wqv, aq[5]);
    aq[6] = fmaf(xb.z, wqv, aq[6]); aq[7] = fmaf(xb.w, wqv, aq[7]);
    ak[0] = fmaf(xa.x, wkv, ak[0]); ak[1] = fmaf(xa.y, wkv, ak[1]);
    ak[2] = fmaf(xa.z, wkv, ak[2]); ak[3] = fmaf(xa.w, wkv, ak[3]);
    ak[4] = fmaf(xb.x, wkv, ak[4]); ak[5] = fmaf(xb.y, wkv, ak[5]);
    ak[6] = fmaf(xb.z, wkv, ak[6]); ak[7] = fmaf(xb.w, wkv, ak[7]);
    av[0] = fmaf(xa.x, wvv, av[0]); av[1] = fmaf(xa.y, wvv, av[1]);
    av[2] = fmaf(xa.z, wvv, av[2]); av[3] = fmaf(xa.w, wvv, av[3]);
    av[4] = fmaf(xb.x, wvv, av[4]); av[5] = fmaf(xb.y, wvv, av[5]);
    av[6] = fmaf(xb.z, wvv, av[6]); av[7] = fmaf(xb.w, wvv, av[7]);
  }
  const float bqv = bq[o], bkv = bk[o], bvv = bv[o];
  const size_t base = (size_t)(r0 + half * 8) * ND + o;
#pragma unroll
  for (int j = 0; j < 8; ++j) {
    Q[base + (size_t)j * ND] = aq[j] + bqv;
    K[base + (size_t)j * ND] = ak[j] + bkv;
    V[base + (size_t)j * ND] = av[j] + bvv;
  }
}

// ---------------- out = msgn @ W + b: 16 rows/block ----------------
__global__ __launch_bounds__(256) void proj128(const float* __restrict__ x,
                                               const float* __restrict__ W,
                                               const float* __restrict__ b,
                                               float* __restrict__ y) {
  __shared__ float xs[ND][20];
  const int r0 = blockIdx.x * 16;
  const int tid = threadIdx.x;
  for (int i = tid; i < 16 * ND; i += 256) {
    int r = i >> 7, c = i & 127;
    xs[c][r] = x[(size_t)(r0 + r) * ND + c];
  }
  __syncthreads();
  const int o = tid & 127;
  const int half = tid >> 7;
  float a[8];
#pragma unroll
  for (int j = 0; j < 8; ++j) a[j] = 0.f;
#pragma unroll 8
  for (int k = 0; k < ND; ++k) {
    float4 xa = *(const float4*)&xs[k][half * 8];
    float4 xb = *(const float4*)&xs[k][half * 8 + 4];
    float w = W[k * ND + o];
    a[0] = fmaf(xa.x, w, a[0]); a[1] = fmaf(xa.y, w, a[1]);
    a[2] = fmaf(xa.z, w, a[2]); a[3] = fmaf(xa.w, w, a[3]);
    a[4] = fmaf(xb.x, w, a[4]); a[5] = fmaf(xb.y, w, a[5]);
    a[6] = fmaf(xb.z, w, a[6]); a[7] = fmaf(xb.w, w, a[7]);
  }
  const float bb = b[o];
  const size_t base = (size_t)(r0 + half * 8) * ND + o;
#pragma unroll
  for (int j = 0; j < 8; ++j) y[base + (size_t)j * ND] = a[j] + bb;
}

// ---------------- CSR build ----------------
__global__ __launch_bounds__(256) void k_hist(const int* __restrict__ ei,
                                              int* __restrict__ hist) {
  int e = blockIdx.x * 256 + threadIdx.x;
  if (e < NE) atomicAdd(&hist[ei[e]], 1);
}

__global__ __launch_bounds__(256) void k_scan1(const int* __restrict__ hist,
                                               int* __restrict__ off,
                                               int* __restrict__ bsum) {
  __shared__ int sh[256];
  const int tid = threadIdx.x;
  const int idx = blockIdx.x * 256 + tid;
  int v = (idx < NN) ? hist[idx] : 0;
  sh[tid] = v;
  __syncthreads();
#pragma unroll
  for (int d = 1; d < 256; d <<= 1) {
    int t = (tid >= d) ? sh[tid - d] : 0;
    __syncthreads();
    sh[tid] += t;
    __syncthreads();
  }
  if (idx < NN) off[idx] = sh[tid] - v;
  if (tid == 255) bsum[blockIdx.x] = sh[255];
}

__global__ __launch_bounds__(256) void k_scan2(int* __restrict__ bsum) {
  __shared__ int sh[256];
  const int tid = threadIdx.x;
  int v = (tid < SCAN_NBLK) ? bsum[tid] : 0;
  sh[tid] = v;
  __syncthreads();
#pragma unroll
  for (int d = 1; d < 256; d <<= 1) {
    int t = (tid >= d) ? sh[tid - d] : 0;
    __syncthreads();
    sh[tid] += t;
    __syncthreads();
  }
  if (tid < SCAN_NBLK) bsum[tid] = sh[tid] - v;
}

__global__ __launch_bounds__(256) void k_scan3(int* __restrict__ off,
                                               const int* __restrict__ bsum,
                                               int* __restrict__ cursor) {
  const int idx = blockIdx.x * 256 + threadIdx.x;
  if (idx < NN) {
    int o = off[idx] + bsum[blockIdx.x];
    off[idx] = o;
    cursor[idx] = o;
  }
  if (blockIdx.x == 0 && threadIdx.x == 0) off[NN] = NE;
}

__global__ __launch_bounds__(256) void k_scatter(const int* __restrict__ ei,
                                                 int* __restrict__ cursor,
                                                 int2* __restrict__ pair) {
  int e = blockIdx.x * 256 + threadIdx.x;
  if (e >= NE) return;
  int row = ei[e];
  int col = ei[NE + e];
  int pos = atomicAdd(&cursor[row], 1);
  pair[pos] = make_int2(col, e);
}

// ---------------- fused gather: 32 lanes/node, ea staged in LDS ----------------
// group g = threadIdx.x>>5 (one node), lane l = (h<<2)|q.
// Per 8-edge chunk: 32 lanes stage 8x256B of ea into LDS once; all heads read
// from LDS (was 8x redundant L2/L3 reads). Intra-wave exchange: no barrier,
// just lgkmcnt(0)+sched_barrier (rule #18).
__global__ __launch_bounds__(256) void k_gather(const float* __restrict__ Q,
                                                const float* __restrict__ K,
                                                const float* __restrict__ V,
                                                const float* __restrict__ we,
                                                const float* __restrict__ be,
                                                const float* __restrict__ ea,
                                                const int* __restrict__ off,
                                                const int2* __restrict__ pair,
                                                float* __restrict__ msgn) {
  __shared__ float eas[8][8 * ED];   // [group][edge][64] = 16 KB
  const int g = threadIdx.x >> 5;
  const int n = blockIdx.x * 8 + g;
  const int l = threadIdx.x & 31;
  const int h = l >> 2;
  const int q = l & 3;

  float qf[DK];
  {
    const float4* qp = (const float4*)(Q + (size_t)n * ND + h * DK);
#pragma unroll
    for (int i = 0; i < 4; ++i) {
      float4 v = qp[i];
      qf[4 * i + 0] = v.x; qf[4 * i + 1] = v.y;
      qf[4 * i + 2] = v.z; qf[4 * i + 3] = v.w;
    }
  }

  float sbase = 0.f;
  {
    const float4* bp = (const float4*)(be + h * DK);
#pragma unroll
    for (int i = 0; i < 4; ++i) {
      float4 b = bp[i];
      sbase = fmaf(qf[4 * i + 0], b.x, sbase);
      sbase = fmaf(qf[4 * i + 1], b.y, sbase);
      sbase = fmaf(qf[4 * i + 2], b.z, sbase);
      sbase = fmaf(qf[4 * i + 3], b.w, sbase);
    }
  }
  const float sb = sbase * 0.25f;

  float gg[16];
#pragma unroll
  for (int jj = 0; jj < 16; ++jj) {
    const float4* wp = (const float4*)(we + (size_t)(q * 16 + jj) * ND + h * DK);
    float s = 0.f;
#pragma unroll
    for (int i = 0; i < 4; ++i) {
      float4 w = wp[i];
      s = fmaf(qf[4 * i + 0], w.x, s);
      s = fmaf(qf[4 * i + 1], w.y, s);
      s = fmaf(qf[4 * i + 2], w.z, s);
      s = fmaf(qf[4 * i + 3], w.w, s);
    }
    gg[jj] = s;
  }

  float4 qv;
  qv.x = qf[q * 4 + 0]; qv.y = qf[q * 4 + 1];
  qv.z = qf[q * 4 + 2]; qv.w = qf[q * 4 + 3];

  float4 acc = make_float4(0.f, 0.f, 0.f, 0.f);
  float den = 0.f;

  const int j0 = off[n], j1 = off[n + 1];
  const int hq = h * DK + q * 4;

  for (int jp = j0; jp < j1; jp += 8) {
    const int nc = min(8, j1 - jp);

    // --- stage: pair + ea chunk into LDS ---
    int2 p = make_int2(0, 0);
    if (l < nc) p = pair[jp + l];
    {
      const int eidx = __shfl(p.y, l >> 2, 32);   // edge id of chunk-edge l>>2
      if (l < 4 * nc) {
        const float4* src = (const float4*)(ea + (size_t)eidx * ED) + (l & 3);
        float4 a0 = src[0], a1 = src[4], a2 = src[8], a3 = src[12];
        float4* dst = (float4*)&eas[g][(l >> 2) * ED] + (l & 3);
        dst[0] = a0; dst[4] = a1; dst[8] = a2; dst[12] = a3;
      }
    }
    asm volatile("s_waitcnt lgkmcnt(0)" ::: "memory");
    __builtin_amdgcn_sched_barrier(0);

    int c = 0;
    for (; c + 4 <= nc; c += 4) {
      const int col0 = __shfl(p.x, c + 0, 32);
      const int col1 = __shfl(p.x, c + 1, 32);
      const int col2 = __shfl(p.x, c + 2, 32);
      const int col3 = __shfl(p.x, c + 3, 32);

      const float4 k0 = *(const float4*)(K + (size_t)col0 * ND + hq);
      const float4 k1 = *(const float4*)(K + (size_t)col1 * ND + hq);
      const float4 k2 = *(const float4*)(K + (size_t)col2 * ND + hq);
      const float4 k3 = *(const float4*)(K + (size_t)col3 * ND + hq);
      const float4 v0 = *(const float4*)(V + (size_t)col0 * ND + hq);
      const float4 v1 = *(const float4*)(V + (size_t)col1 * ND + hq);
      const float4 v2 = *(const float4*)(V + (size_t)col2 * ND + hq);
      const float4 v3 = *(const float4*)(V + (size_t)col3 * ND + hq);

      float s0 = k0.x * qv.x; s0 = fmaf(qv.y, k0.y, s0); s0 = fmaf(qv.z, k0.z, s0); s0 = fmaf(qv.w, k0.w, s0);
      float s1 = k1.x * qv.x; s1 = fmaf(qv.y, k1.y, s1); s1 = fmaf(qv.z, k1.z, s1); s1 = fmaf(qv.w, k1.w, s1);
      float s2 = k2.x * qv.x; s2 = fmaf(qv.y, k2.y, s2); s2 = fmaf(qv.z, k2.z, s2); s2 = fmaf(qv.w, k2.w, s2);
      float s3 = k3.x * qv.x; s3 = fmaf(qv.y, k3.y, s3); s3 = fmaf(qv.z, k3.z, s3); s3 = fmaf(qv.w, k3.w, s3);

      const float4* e0 = (const float4*)&eas[g][(c + 0) * ED + q * 16];
      const float4* e1 = (const float4*)&eas[g][(c + 1) * ED + q * 16];
      const float4* e2 = (const float4*)&eas[g][(c + 2) * ED + q * 16];
      const float4* e3 = (const float4*)&eas[g][(c + 3) * ED + q * 16];
#pragma unroll
      for (int i = 0; i < 4; ++i) {
        float4 a = e0[i];
        s0 = fmaf(a.x, gg[4 * i + 0], s0); s0 = fmaf(a.y, gg[4 * i + 1], s0);
        s0 = fmaf(a.z, gg[4 * i + 2], s0); s0 = fmaf(a.w, gg[4 * i + 3], s0);
      }
#pragma unroll
      for (int i = 0; i < 4; ++i) {
        float4 a = e1[i];
        s1 = fmaf(a.x, gg[4 * i + 0], s1); s1 = fmaf(a.y, gg[4 * i + 1], s1);
        s1 = fmaf(a.z, gg[4 * i + 2], s1); s1 = fmaf(a.w, gg[4 * i + 3], s1);
      }
#pragma unroll
      for (int i = 0; i < 4; ++i) {
        float4 a = e2[i];
        s2 = fmaf(a.x, gg[4 * i + 0], s2); s2 = fmaf(a.y, gg[4 * i + 1], s2);
        s2 = fmaf(a.z, gg[4 * i + 2], s2); s2 = fmaf(a.w, gg[4 * i + 3], s2);
      }
#pragma unroll
      for (int i = 0; i < 4; ++i) {
        float4 a = e3[i];
        s3 = fmaf(a.x, gg[4 * i + 0], s3); s3 = fmaf(a.y, gg[4 * i + 1], s3);
        s3 = fmaf(a.z, gg[4 * i + 2], s3); s3 = fmaf(a.w, gg[4 * i + 3], s3);
      }

      s0 += __shfl_xor(s0, 1); s0 += __shfl_xor(s0, 2);
      s1 += __shfl_xor(s1, 1); s1 += __shfl_xor(s1, 2);
      s2 += __shfl_xor(s2, 1); s2 += __shfl_xor(s2, 2);
      s3 += __shfl_xor(s3, 1); s3 += __shfl_xor(s3, 2);

      const float es0 = __expf(fmaf(s0, 0.25f, sb));
      const float es1 = __expf(fmaf(s1, 0.25f, sb));
      const float es2 = __expf(fmaf(s2, 0.25f, sb));
      const float es3 = __expf(fmaf(s3, 0.25f, sb));
      den += (es0 + es1) + (es2 + es3);

      acc.x = fmaf(es0, v0.x, acc.x); acc.y = fmaf(es0, v0.y, acc.y);
      acc.z = fmaf(es0, v0.z, acc.z); acc.w = fmaf(es0, v0.w, acc.w);
      acc.x = fmaf(es1, v1.x, acc.x); acc.y = fmaf(es1, v1.y, acc.y);
      acc.z = fmaf(es1, v1.z, acc.z); acc.w = fmaf(es1, v1.w, acc.w);
      acc.x = fmaf(es2, v2.x, acc.x); acc.y = fmaf(es2, v2.y, acc.y);
      acc.z = fmaf(es2, v2.z, acc.z); acc.w = fmaf(es2, v2.w, acc.w);
      acc.x = fmaf(es3, v3.x, acc.x); acc.y = fmaf(es3, v3.y, acc.y);
      acc.z = fmaf(es3, v3.z, acc.z); acc.w = fmaf(es3, v3.w, acc.w);
    }

    for (; c < nc; ++c) {
      const int col = __shfl(p.x, c, 32);
      const float4 kv = *(const float4*)(K + (size_t)col * ND + hq);
      const float4 vv = *(const float4*)(V + (size_t)col * ND + hq);
      float s = kv.x * qv.x;
      s = fmaf(qv.y, kv.y, s); s = fmaf(qv.z, kv.z, s); s = fmaf(qv.w, kv.w, s);
      const float4* ep = (const float4*)&eas[g][c * ED + q * 16];
#pragma unroll
      for (int i = 0; i < 4; ++i) {
        float4 a = ep[i];
        s = fmaf(a.x, gg[4 * i + 0], s); s = fmaf(a.y, gg[4 * i + 1], s);
        s = fmaf(a.z, gg[4 * i + 2], s); s = fmaf(a.w, gg[4 * i + 3], s);
      }
      s += __shfl_xor(s, 1); s += __shfl_xor(s, 2);
      const float es = __expf(fmaf(s, 0.25f, sb));
      den += es;
      acc.x = fmaf(es, vv.x, acc.x); acc.y = fmaf(es, vv.y, acc.y);
      acc.z = fmaf(es, vv.z, acc.z); acc.w = fmaf(es, vv.w, acc.w);
    }
  }

  const float inv = 1.f / (den + 1e-8f);
  float4 o;
  o.x = acc.x * inv; o.y = acc.y * inv; o.z = acc.z * inv; o.w = acc.w * inv;
  *(float4*)(msgn + (size_t)n * ND + h * DK + q * 4) = o;
}

extern "C" void kernel_launch(void* const* d_in, const int* in_sizes, int n_in,
                              void* d_out, int out_size, void* d_ws, size_t ws_size,
                              hipStream_t stream) {
  const float* nodes = (const float*)d_in[0];
  const int*   ei    = (const int*)d_in[1];
  const float* ea    = (const float*)d_in[2];
  const float* wq    = (const float*)d_in[3];
  const float* bq    = (const float*)d_in[4];
  const float* wk    = (const float*)d_in[5];
  const float* bk    = (const float*)d_in[6];
  const float* wv    = (const float*)d_in[7];
  const float* bv    = (const float*)d_in[8];
  const float* we    = (const float*)d_in[9];
  const float* be    = (const float*)d_in[10];
  const float* wo    = (const float*)d_in[11];
  const float* bo    = (const float*)d_in[12];
  float* out = (float*)d_out;

  float* ws = (float*)d_ws;
  const size_t NND = (size_t)NN * ND;
  float* Q    = ws;
  float* K    = Q + NND;
  float* V    = K + NND;
  float* msgn = V + NND;
  int* hist   = (int*)(msgn + NND);
  int* off    = hist + NN;            // NN+1 (padded to 40004)
  int* cursor = off + 40004;
  int* bsum   = cursor + NN;
  int2* pair  = (int2*)(bsum + 256);  // NE int2

  hipMemsetAsync(hist, 0, NN * sizeof(int), stream);

  dim3 blk(256);

  proj_qkv<<<dim3(NN / 16), blk, 0, stream>>>(nodes, wq, bq, wk, bk, wv, bv, Q, K, V);

  dim3 gE((NE + 255) / 256);
  k_hist<<<gE, blk, 0, stream>>>(ei, hist);
  k_scan1<<<dim3(SCAN_NBLK), blk, 0, stream>>>(hist, off, bsum);
  k_scan2<<<dim3(1), blk, 0, stream>>>(bsum);
  k_scan3<<<dim3(SCAN_NBLK), blk, 0, stream>>>(off, bsum, cursor);
  k_scatter<<<gE, blk, 0, stream>>>(ei, cursor, pair);

  k_gather<<<dim3(NN / 8), blk, 0, stream>>>(Q, K, V, we, be, ea, off, pair, msgn);

  proj128<<<dim3(NN / 16), blk, 0, stream>>>(msgn, wo, bo, out);
}